// Round 6
// baseline (347.487 us; speedup 1.0000x reference)
//
#include <hip/hip_runtime.h>

// RNN: h_t = tanh(x_t * W_ih^T + b_ih + h_{t-1} W_hh^T + b_hh), out = h_T W_fc^T + b_fc
// B=8192, T=784, I=1, H=30 (pad 32), C=10. fp32.
//
// R8: two-batch-per-lane software pipeline. R7 falsified "instruction count"
// theories: pk_fma is 4clk/wave64 (fp32 FMA pipe = 32 lanes/clk, packing
// saves issue slots only), so R6==R7. Measured 890 clk/SIMD-step vs ~560
// issue => ~24% of time BOTH waves sit in the tanh latency tail (random
// phase alignment, VALUBusy 76%). Fix is structural: each lane carries TWO
// batches (A,B); B's tanh stages are woven between A's MAC chunks (and
// vice versa) with sched_barrier(0) fences, so every tanh latency window
// (~80clk) hides under the other group's MAC block (~180clk). Weights are
// batch-independent => shared registers; only h/acc state duplicates.
// Grid: 512 blocks x 128 thr = 1024 waves = 1/SIMD (waves_per_eu(1,1));
// in-wave ILP replaces the lost 2nd wave, dual-stall windows vanish.
// Keeps proven pieces: PK2 DPP-broadcast+pk_fma MACs (R7), volatile weight
// pins (R6), identical tanh numerics (absmax 2^-10 since R2).

#define BB 8192
#define TT 784
#define HH 30
#define CC 10
#define NBB 16     // batches per 128-thread block (8 per wave)
#define LSTR 36    // LDS row stride (floats) for the final FC exchange

#define SB() __builtin_amdgcn_sched_barrier(0)

typedef __attribute__((ext_vector_type(2))) float f32x2;

// Two k-groups: broadcast H0/H1 from lanes K0,K1 of the 16-lane DPP row into
// v[40:41]/v[42:43], then 4 v_pk_fma_f32 (8 MACs). Proven correct in R7.
#define PK2(H0, H1, A0, A1, K0, K1)                                          \
    asm volatile(                                                            \
        "v_mov_b32_dpp v40, %2 row_newbcast:" #K0 " row_mask:0xf bank_mask:0xf\n\t" \
        "v_mov_b32_dpp v41, %3 row_newbcast:" #K0 " row_mask:0xf bank_mask:0xf\n\t" \
        "v_mov_b32_dpp v42, %2 row_newbcast:" #K1 " row_mask:0xf bank_mask:0xf\n\t" \
        "v_mov_b32_dpp v43, %3 row_newbcast:" #K1 " row_mask:0xf bank_mask:0xf\n\t" \
        "v_pk_fma_f32 %0, %4, v[40:41], %0\n\t"                              \
        "v_pk_fma_f32 %1, %5, v[40:41], %1\n\t"                              \
        "v_pk_fma_f32 %0, %6, v[42:43], %0\n\t"                              \
        "v_pk_fma_f32 %1, %7, v[42:43], %1"                                  \
        : "+v"(A0), "+v"(A1)                                                 \
        : "v"(H0), "v"(H1), "v"(w0p[K0]), "v"(w1p[K0]),                      \
          "v"(w0p[K1]), "v"(w1p[K1])                                         \
        : "v40", "v41", "v42", "v43")

#define PK1(H0, H1, A0, A1, K0)                                              \
    asm volatile(                                                            \
        "v_mov_b32_dpp v40, %2 row_newbcast:" #K0 " row_mask:0xf bank_mask:0xf\n\t" \
        "v_mov_b32_dpp v41, %3 row_newbcast:" #K0 " row_mask:0xf bank_mask:0xf\n\t" \
        "v_pk_fma_f32 %0, %4, v[40:41], %0\n\t"                              \
        "v_pk_fma_f32 %1, %5, v[40:41], %1"                                  \
        : "+v"(A0), "+v"(A1)                                                 \
        : "v"(H0), "v"(H1), "v"(w0p[K0]), "v"(w1p[K0])                       \
        : "v40", "v41")

__global__ __launch_bounds__(128)
__attribute__((amdgpu_waves_per_eu(1, 1)))
void rnn_scan_kernel(const float* __restrict__ x,
                     const float* __restrict__ W_ih,
                     const float* __restrict__ W_hh,
                     const float* __restrict__ b_ih,
                     const float* __restrict__ b_hh,
                     const float* __restrict__ W_fc,
                     const float* __restrict__ b_fc,
                     float* __restrict__ out) {
    __shared__ float hbuf[NBB * LSTR];

    const int tid  = threadIdx.x;
    const int wv   = tid >> 6;         // wave 0..1
    const int lane = tid & 63;
    const int row  = lane >> 4;        // DPP row 0..3 = batch-pair slot
    const int r    = lane & 15;        // lane within the 16-lane DPP row
    const int i0   = r * 2;            // owned rows i0, i0+1
    const int lbA  = wv * 8 + row * 2; // local batch index of A (B = +1)
    const int bA   = blockIdx.x * NBB + lbA;
    const int bB   = bA + 1;

    // --- per-lane weights: rows i0,i0+1 as 15 column-pairs (cols 0..29;
    // cols 30,31 structural zeros, k=15 skipped). Shared by batches A,B. ---
    f32x2 w0p[15], w1p[15];
    const bool v0 = (i0 < HH), v1 = (i0 + 1 < HH);
#pragma unroll
    for (int k = 0; k < 15; ++k) {
        const int c0 = 2 * k, c1 = 2 * k + 1;
        w0p[k].x = v0 ? W_hh[i0 * HH + c0] : 0.0f;
        w0p[k].y = v0 ? W_hh[i0 * HH + c1] : 0.0f;
        w1p[k].x = v1 ? W_hh[(i0 + 1) * HH + c0] : 0.0f;
        w1p[k].y = v1 ? W_hh[(i0 + 1) * HH + c1] : 0.0f;
    }
    float bias0 = v0 ? (b_ih[i0] + b_hh[i0]) : 0.0f;
    float bias1 = v1 ? (b_ih[i0 + 1] + b_hh[i0 + 1]) : 0.0f;
    float wih0  = v0 ? W_ih[i0] : 0.0f;
    float wih1  = v1 ? W_ih[i0 + 1] : 0.0f;

    // volatile pins (R6-proven): weights stay VGPR-resident for the scan.
#pragma unroll
    for (int k = 0; k < 15; ++k) {
        asm volatile("" : "+v"(w0p[k]));
        asm volatile("" : "+v"(w1p[k]));
    }
    asm volatile("" : "+v"(bias0));
    asm volatile("" : "+v"(bias1));
    asm volatile("" : "+v"(wih0));
    asm volatile("" : "+v"(wih1));

    // State: lane r holds h[2r],h[2r+1] for batches A and B.
    // accB=0 init => woven B-tanh at t=0 yields hB(0)=1-2*rcp(2)=0 exactly.
    float hA0 = 0.0f, hA1 = 0.0f, hB0 = 0.0f, hB1 = 0.0f;
    f32x2 accA0 = {0.f, 0.f}, accA1 = {0.f, 0.f};
    f32x2 accB0 = {0.f, 0.f}, accB1 = {0.f, 0.f};

    const float* xa = x + (size_t)bA * TT;
    const float* xb = x + (size_t)bB * TT;
    float4 xqA = *(const float4*)xa;
    float4 xqB = *(const float4*)xb;

    for (int q = 0; q < TT / 4; ++q) {
        const bool more = (q + 1 < TT / 4);
        float4 nA = more ? *(const float4*)(xa + (q + 1) * 4) : make_float4(0,0,0,0);
        float4 nB = more ? *(const float4*)(xb + (q + 1) * 4) : make_float4(0,0,0,0);
#pragma unroll
        for (int u = 0; u < 4; ++u) {
            const float xtA = (u == 0) ? xqA.x : (u == 1) ? xqA.y
                            : (u == 2) ? xqA.z : xqA.w;
            const float xtB = (u == 0) ? xqB.x : (u == 1) ? xqB.y
                            : (u == 2) ? xqB.z : xqB.w;

            // ---- A-MAC(t), woven with B-tanh (finishing step t-1) ----
            accA0 = (f32x2){fmaf(xtA, wih0, bias0), 0.0f};
            accA1 = (f32x2){fmaf(xtA, wih1, bias1), 0.0f};
            SB();
            PK2(hA0, hA1, accA0, accA1, 0, 1);
            PK2(hA0, hA1, accA0, accA1, 2, 3);
            PK2(hA0, hA1, accA0, accA1, 4, 5);
            PK2(hA0, hA1, accA0, accA1, 6, 7);
            const float sB0 = accB0.x + accB0.y;
            const float sB1 = accB1.x + accB1.y;
            SB();
            PK2(hA0, hA1, accA0, accA1, 8, 9);
            PK2(hA0, hA1, accA0, accA1, 10, 11);
            const float eB0 = __expf(2.0f * sB0);
            const float eB1 = __expf(2.0f * sB1);
            SB();
            PK2(hA0, hA1, accA0, accA1, 12, 13);
            const float rB0 = __builtin_amdgcn_rcpf(eB0 + 1.0f);
            const float rB1 = __builtin_amdgcn_rcpf(eB1 + 1.0f);
            SB();
            PK1(hA0, hA1, accA0, accA1, 14);
            hB0 = 1.0f - 2.0f * rB0;
            hB1 = 1.0f - 2.0f * rB1;
            SB();

            // ---- B-MAC(t), woven with A-tanh (step t) ----
            // (accB inits sit between hB writes and the DPP reads of hB:
            //  >=3 instr gap covers the VALU-write->DPP-read hazard.)
            accB0 = (f32x2){fmaf(xtB, wih0, bias0), 0.0f};
            accB1 = (f32x2){fmaf(xtB, wih1, bias1), 0.0f};
            SB();
            PK2(hB0, hB1, accB0, accB1, 0, 1);
            PK2(hB0, hB1, accB0, accB1, 2, 3);
            PK2(hB0, hB1, accB0, accB1, 4, 5);
            PK2(hB0, hB1, accB0, accB1, 6, 7);
            const float sA0 = accA0.x + accA0.y;
            const float sA1 = accA1.x + accA1.y;
            SB();
            PK2(hB0, hB1, accB0, accB1, 8, 9);
            PK2(hB0, hB1, accB0, accB1, 10, 11);
            const float eA0 = __expf(2.0f * sA0);
            const float eA1 = __expf(2.0f * sA1);
            SB();
            PK2(hB0, hB1, accB0, accB1, 12, 13);
            const float rA0 = __builtin_amdgcn_rcpf(eA0 + 1.0f);
            const float rA1 = __builtin_amdgcn_rcpf(eA1 + 1.0f);
            SB();
            PK1(hB0, hB1, accB0, accB1, 14);
            hA0 = 1.0f - 2.0f * rA0;
            hA1 = 1.0f - 2.0f * rA1;
            SB();
        }
        xqA = nA;
        xqB = nB;
    }

    // B's last step: tanh not yet applied (A's was woven into the last B-MAC)
    {
        const float sB0 = accB0.x + accB0.y;
        const float sB1 = accB1.x + accB1.y;
        hB0 = 1.0f - 2.0f * __builtin_amdgcn_rcpf(__expf(2.0f * sB0) + 1.0f);
        hB1 = 1.0f - 2.0f * __builtin_amdgcn_rcpf(__expf(2.0f * sB1) + 1.0f);
    }

    // --- FC head: park final h in LDS (wave-local), lanes r<10 do outputs.
    float* hpA = &hbuf[lbA * LSTR];
    float* hpB = &hbuf[(lbA + 1) * LSTR];
    *(float2*)&hpA[i0] = make_float2(hA0, hA1);
    *(float2*)&hpB[i0] = make_float2(hB0, hB1);
    __builtin_amdgcn_wave_barrier();

    if (r < CC) {
        const int c = r;
        float aA = b_fc[c];
        float aB = b_fc[c];
#pragma unroll
        for (int j = 0; j < HH; ++j) {
            const float wfc = W_fc[c * HH + j];
            aA += wfc * hpA[j];
            aB += wfc * hpB[j];
        }
        out[(size_t)bA * CC + c] = aA;
        out[(size_t)bB * CC + c] = aB;
    }
}

extern "C" void kernel_launch(void* const* d_in, const int* in_sizes, int n_in,
                              void* d_out, int out_size, void* d_ws, size_t ws_size,
                              hipStream_t stream) {
    const float* x    = (const float*)d_in[0];
    const float* W_ih = (const float*)d_in[1];
    const float* W_hh = (const float*)d_in[2];
    const float* b_ih = (const float*)d_in[3];
    const float* b_hh = (const float*)d_in[4];
    const float* W_fc = (const float*)d_in[5];
    const float* b_fc = (const float*)d_in[6];

    hipLaunchKernelGGL(rnn_scan_kernel,
                       dim3(BB / NBB), dim3(128), 0, stream,
                       x, W_ih, W_hh, b_ih, b_hh, W_fc, b_fc,
                       (float*)d_out);
}

// Round 7
// 289.074 us; speedup vs baseline: 1.2021x; 1.2021x over previous
//
#include <hip/hip_runtime.h>

// RNN: h_t = tanh(x_t * W_ih^T + b_ih + h_{t-1} W_hh^T + b_hh), out = h_T W_fc^T + b_fc
// B=8192, T=784, I=1, H=30 (pad 32), C=10. fp32.
//
// R9: MFMA. R2-R8 all land at 103-120 clk/batch-step because the fp32 VALU
// MAC pipe (32 lanes/clk) is the floor of any broadcast-MAC decomposition
// (28 clk/batch MAC + ~30 broadcast + ~15 tanh). The matrix pipe is idle
// (MfmaUtil=0 all session). This kernel does h*W_hh^T as 2 MFMA tiles of
// mfma_f32_16x16x32_bf16 (M=16x2 W-rows, K=32>=30 h-dim, N=16 batches/wave),
// with:
//  * split-float precision: W=Whi+Wlo, h=hhi+hlo (bf16+bf16 residual);
//    Whi*hhi + Whi*hlo + Wlo*hhi (3 MFMAs; dropped lo*lo <= ~1e-4/step,
//    contractive recurrence -> ~2e-4 final, under the ~1e-3 tanh noise).
//  * row-permuted A operand: tile1 row m holds W row s1(m)=8(m>>2)+(m&3),
//    tile2 s2(m)=s1(m)+4. Then D (col=lane&15, row=4g+r; m89-verified)
//    lands h[8g+r] / h[8g+4+r] in lane (g=L>>4, n=L&15) == EXACTLY the
//    B-fragment (col=lane&15, k=8g+j) this lane supplies next step.
//    Zero cross-lane movement per step. W rows 30,31 are zero rows ->
//    h[30]=h[31]=tanh(0)=0 automatically.
//  * bias + x_t*W_ih enters through the MFMA C operand (8 VALU fma).
//  * no LDS; FC head reduces across the 4 lane-groups with shfl_xor.
// Grid: 512 blocks x 64 thr (1 wave, 16 batches); waves_per_eu(1,1) spreads
// 512 waves across 1024 SIMDs (and keeps the register budget at 512 so the
// allocator never rematerializes the pinned fragments - R4/R6 lesson).

#define BB 8192
#define TT 784
#define HH 30
#define CC 10

typedef __attribute__((ext_vector_type(8))) short  bf16x8;
typedef __attribute__((ext_vector_type(4))) float  f32x4;
typedef __attribute__((ext_vector_type(4))) unsigned uint4v;

__device__ __forceinline__ float tanh_fast(float a) {
    // identical numerics to R2..R8 (absmax 2^-10 all session)
    return 1.0f - 2.0f * __builtin_amdgcn_rcpf(__expf(2.0f * a) + 1.0f);
}

// (p0,p1) f32 -> packed bf16 pair hp (RNE) + packed bf16 residual pair lp.
// v_cvt_pk_bf16_f32: %1 -> low half (even k), %2 -> high half (odd k).
#define BPAIR(p0, p1, hp, lp) do {                                          \
    asm("v_cvt_pk_bf16_f32 %0, %1, %2" : "=v"(hp) : "v"(p0), "v"(p1));      \
    const float _h0 = __uint_as_float((hp) << 16);                          \
    const float _h1 = __uint_as_float((hp) & 0xffff0000u);                  \
    const float _l0 = (p0) - _h0;                                           \
    const float _l1 = (p1) - _h1;                                           \
    asm("v_cvt_pk_bf16_f32 %0, %1, %2" : "=v"(lp) : "v"(_l0), "v"(_l1));    \
} while (0)

__global__ __launch_bounds__(64)
__attribute__((amdgpu_waves_per_eu(1, 1)))
void rnn_scan_kernel(const float* __restrict__ x,
                     const float* __restrict__ W_ih,
                     const float* __restrict__ W_hh,
                     const float* __restrict__ b_ih,
                     const float* __restrict__ b_hh,
                     const float* __restrict__ W_fc,
                     const float* __restrict__ b_fc,
                     float* __restrict__ out) {
    const int lane = threadIdx.x & 63;
    const int n    = lane & 15;          // batch column (A row index too)
    const int g    = lane >> 4;          // k-group / D-row group
    const int b    = blockIdx.x * 16 + n;

    // ---- A fragments: per-lane row n of each tile, k = 8g..8g+7 ----
    const int r1 = 8 * (n >> 2) + (n & 3);   // tile1 W-row, always <= 27
    const int r2 = r1 + 4;                    // tile2 W-row, 30/31 -> zero row
    unsigned a1h[4], a1l[4], a2h[4], a2l[4];
#pragma unroll
    for (int d = 0; d < 4; ++d) {
        const int k0 = 8 * g + 2 * d, k1 = k0 + 1;
        const float w1a = (k0 < HH) ? W_hh[r1 * HH + k0] : 0.f;
        const float w1b = (k1 < HH) ? W_hh[r1 * HH + k1] : 0.f;
        const float w2a = (r2 < HH && k0 < HH) ? W_hh[r2 * HH + k0] : 0.f;
        const float w2b = (r2 < HH && k1 < HH) ? W_hh[r2 * HH + k1] : 0.f;
        const unsigned u1a = __float_as_uint(w1a), u1b = __float_as_uint(w1b);
        const unsigned u2a = __float_as_uint(w2a), u2b = __float_as_uint(w2b);
        // hi = truncation to bf16 (low half = even k); lo = residual, truncated
        a1h[d] = (u1b & 0xffff0000u) | (u1a >> 16);
        a2h[d] = (u2b & 0xffff0000u) | (u2a >> 16);
        const float l1a = w1a - __uint_as_float(u1a & 0xffff0000u);
        const float l1b = w1b - __uint_as_float(u1b & 0xffff0000u);
        const float l2a = w2a - __uint_as_float(u2a & 0xffff0000u);
        const float l2b = w2b - __uint_as_float(u2b & 0xffff0000u);
        a1l[d] = (__float_as_uint(l1b) & 0xffff0000u) | (__float_as_uint(l1a) >> 16);
        a2l[d] = (__float_as_uint(l2b) & 0xffff0000u) | (__float_as_uint(l2a) >> 16);
    }
    bf16x8 A1h = __builtin_bit_cast(bf16x8, (uint4v){a1h[0], a1h[1], a1h[2], a1h[3]});
    bf16x8 A1l = __builtin_bit_cast(bf16x8, (uint4v){a1l[0], a1l[1], a1l[2], a1l[3]});
    bf16x8 A2h = __builtin_bit_cast(bf16x8, (uint4v){a2h[0], a2h[1], a2h[2], a2h[3]});
    bf16x8 A2l = __builtin_bit_cast(bf16x8, (uint4v){a2l[0], a2l[1], a2l[2], a2l[3]});
    // volatile pins: defs cannot be sunk into the loop (R4/R6 lesson)
    asm volatile("" : "+v"(A1h), "+v"(A1l), "+v"(A2h), "+v"(A2l));

    // ---- C-init params: D rows of this lane are h-rows 8g+r / 8g+4+r ----
    float bias1[4], wih1[4], bias2[4], wih2[4];
#pragma unroll
    for (int r = 0; r < 4; ++r) {
        const int q1 = 8 * g + r;                       // <= 27
        bias1[r] = b_ih[q1] + b_hh[q1];
        wih1[r]  = W_ih[q1];
        const int q2 = q1 + 4;                          // 30/31 -> zero
        bias2[r] = (q2 < HH) ? (b_ih[q2] + b_hh[q2]) : 0.f;
        wih2[r]  = (q2 < HH) ? W_ih[q2] : 0.f;
        asm volatile("" : "+v"(bias1[r]), "+v"(wih1[r]), "+v"(bias2[r]), "+v"(wih2[r]));
    }

    // h state: lane holds h[8g+j], j=0..7 (j<4 from tile1, j>=4 from tile2)
    float h0 = 0.f, h1 = 0.f, h2 = 0.f, h3 = 0.f;
    float h4 = 0.f, h5 = 0.f, h6 = 0.f, h7 = 0.f;

    const float* xp = x + (size_t)b * TT;
    float4 xq = *(const float4*)xp;

    for (int qq = 0; qq < TT / 4; ++qq) {
        const float4 nxt = (qq + 1 < TT / 4) ? *(const float4*)(xp + (qq + 1) * 4)
                                             : make_float4(0.f, 0.f, 0.f, 0.f);
#pragma unroll
        for (int u = 0; u < 4; ++u) {
            const float xt = (u == 0) ? xq.x : (u == 1) ? xq.y
                           : (u == 2) ? xq.z : xq.w;
            f32x4 acc1 = { fmaf(xt, wih1[0], bias1[0]), fmaf(xt, wih1[1], bias1[1]),
                           fmaf(xt, wih1[2], bias1[2]), fmaf(xt, wih1[3], bias1[3]) };
            f32x4 acc2 = { fmaf(xt, wih2[0], bias2[0]), fmaf(xt, wih2[1], bias2[1]),
                           fmaf(xt, wih2[2], bias2[2]), fmaf(xt, wih2[3], bias2[3]) };
            // B fragment = this lane's own h, split hi/lo and packed
            unsigned bh0, bh1, bh2, bh3, bl0, bl1, bl2, bl3;
            BPAIR(h0, h1, bh0, bl0);
            BPAIR(h2, h3, bh1, bl1);
            BPAIR(h4, h5, bh2, bl2);
            BPAIR(h6, h7, bh3, bl3);
            const bf16x8 Bh = __builtin_bit_cast(bf16x8, (uint4v){bh0, bh1, bh2, bh3});
            const bf16x8 Bl = __builtin_bit_cast(bf16x8, (uint4v){bl0, bl1, bl2, bl3});
            // 3-MFMA split-float per tile (lo*lo dropped)
            acc1 = __builtin_amdgcn_mfma_f32_16x16x32_bf16(A1h, Bh, acc1, 0, 0, 0);
            acc2 = __builtin_amdgcn_mfma_f32_16x16x32_bf16(A2h, Bh, acc2, 0, 0, 0);
            acc1 = __builtin_amdgcn_mfma_f32_16x16x32_bf16(A1h, Bl, acc1, 0, 0, 0);
            acc2 = __builtin_amdgcn_mfma_f32_16x16x32_bf16(A2h, Bl, acc2, 0, 0, 0);
            acc1 = __builtin_amdgcn_mfma_f32_16x16x32_bf16(A1l, Bh, acc1, 0, 0, 0);
            acc2 = __builtin_amdgcn_mfma_f32_16x16x32_bf16(A2l, Bh, acc2, 0, 0, 0);
            // tanh; rows 30/31 get acc==0 -> exactly 0
            h0 = tanh_fast(acc1[0]); h1 = tanh_fast(acc1[1]);
            h2 = tanh_fast(acc1[2]); h3 = tanh_fast(acc1[3]);
            h4 = tanh_fast(acc2[0]); h5 = tanh_fast(acc2[1]);
            h6 = tanh_fast(acc2[2]); h7 = tanh_fast(acc2[3]);
        }
        xq = nxt;
    }

    // ---- FC head: lane holds h[8g..8g+7]; reduce across the 4 groups ----
    const float hreg[8] = {h0, h1, h2, h3, h4, h5, h6, h7};
#pragma unroll
    for (int c = 0; c < CC; ++c) {
        float p = 0.f;
#pragma unroll
        for (int j = 0; j < 8; ++j) {
            const int k = 8 * g + j;
            if (k < HH) p = fmaf(W_fc[c * HH + k], hreg[j], p);
        }
        p += __shfl_xor(p, 16);
        p += __shfl_xor(p, 32);
        if (g == 0) out[(size_t)b * CC + c] = p + b_fc[c];
    }
}

extern "C" void kernel_launch(void* const* d_in, const int* in_sizes, int n_in,
                              void* d_out, int out_size, void* d_ws, size_t ws_size,
                              hipStream_t stream) {
    const float* x    = (const float*)d_in[0];
    const float* W_ih = (const float*)d_in[1];
    const float* W_hh = (const float*)d_in[2];
    const float* b_ih = (const float*)d_in[3];
    const float* b_hh = (const float*)d_in[4];
    const float* W_fc = (const float*)d_in[5];
    const float* b_fc = (const float*)d_in[6];

    hipLaunchKernelGGL(rnn_scan_kernel,
                       dim3(BB / 16), dim3(64), 0, stream,
                       x, W_ih, W_hh, b_ih, b_hh, W_fc, b_fc,
                       (float*)d_out);
}